// Round 13
// baseline (183.475 us; speedup 1.0000x reference)
//
#include <hip/hip_runtime.h>

// VQ-VAE quantizer eval forward — single-f16 MFMA screen (A=codes, B=z) with
// 16-code-section top-3 tracking + exact section resolve.
// Scan: 128 rows/block; 16 iterations of 128 codes (chunk-PAIRS), 3-deep
// 16KB pair-buffer ring, ONE raw s_barrier per iteration + counted vmcnt.
// Finish: 16-lane-per-row (1M threads). Emit: coalesced d-major epilogue.
// z: [16,64,64,64] f32 (N=65536 rows, D=64), emb: [4096,64] f32
// out: [quantized NCHW 4194304][indices 65536][loss 1] (all f32)

typedef _Float16 half8 __attribute__((ext_vector_type(8)));
typedef float f32x4 __attribute__((ext_vector_type(4)));

#define NCODES 4096
#define DIM 64
#define NROWS 65536
#define OUT_IDX_OFF 4194304
#define OUT_LOSS_OFF 4259840

// ws byte offsets (total ~4.2 MB)
#define WS_EHI   0u            // 4096*64 f16 = 512KB (emb*256)
#define WS_EE    524288u       // 4096 f32 exact sumsq
#define WS_RLOSS 540672u       // 65536 f32
#define WS_TU1   802816u       // [2][65536] f32 u1 (best section min-u est)
#define WS_TK1   1327104u      // [2][65536] int g1 (section base code)
#define WS_TU2   1851392u      // [2][65536] f32 u2
#define WS_TK23  2375680u      // [2][65536] int packed (g2 | g3<<16)
#define WS_TU3   2899968u      // [2][65536] f32 u3
#define WS_TU4   3424256u      // [2][65536] f32 u4 (4th section guard)
#define WS_LISTB 3948544u      // 65536 int
#define WS_CNTB  4210688u      // int
#define WS_PART  4210944u      // 256 f64

// exact numpy-pairwise sum of squares, n=64 (R1-verified)
__device__ __forceinline__ float pairwise_sumsq64(const float* v) {
    float r[8];
#pragma unroll
    for (int j = 0; j < 8; ++j) r[j] = __fmul_rn(v[j], v[j]);
#pragma unroll
    for (int m = 1; m < 8; ++m) {
#pragma unroll
        for (int j = 0; j < 8; ++j)
            r[j] = __fadd_rn(r[j], __fmul_rn(v[8 * m + j], v[8 * m + j]));
    }
    float s01 = __fadd_rn(r[0], r[1]);
    float s23 = __fadd_rn(r[2], r[3]);
    float s45 = __fadd_rn(r[4], r[5]);
    float s67 = __fadd_rn(r[6], r[7]);
    return __fadd_rn(__fadd_rn(s01, s23), __fadd_rn(s45, s67));
}

// exact ref d2 for code k (R1-verified semantics)
__device__ __forceinline__ float exact_d2(const float* __restrict__ emb, int k,
                                          const float* zr, float zz, float eev) {
    const float4* ep = reinterpret_cast<const float4*>(emb + (size_t)k * DIM);
    float da = 0.f;
#pragma unroll
    for (int q = 0; q < 16; ++q) {
        float4 A = ep[q];
        da += A.x * zr[4 * q + 0]; da += A.y * zr[4 * q + 1];
        da += A.z * zr[4 * q + 2]; da += A.w * zr[4 * q + 3];
    }
    return __fadd_rn(__fsub_rn(zz, __fmul_rn(2.0f, da)), eev);
}

// async global->LDS, 16B per lane (linear LDS dest; swizzle lives in the SOURCE addr)
__device__ __forceinline__ void gload_lds16(const void* g, void* l) {
    __builtin_amdgcn_global_load_lds(
        (const __attribute__((address_space(1))) unsigned int*)g,
        (__attribute__((address_space(3))) unsigned int*)l, 16, 0, 0);
}

#define WAITVM(n)                                               \
    {                                                           \
        asm volatile("s_waitcnt vmcnt(" #n ")" ::: "memory");   \
        __builtin_amdgcn_sched_barrier(0);                      \
    }

// prep also zeroes cntB/part (replaces two hipMemsetAsync dispatches)
__global__ void vq_prep(const float* __restrict__ emb, _Float16* __restrict__ ehi,
                        float* __restrict__ ee, int* __restrict__ cntB,
                        double* __restrict__ part) {
    if (blockIdx.x == 0) {
        part[threadIdx.x] = 0.0;
        if (threadIdx.x == 0) *cntB = 0;
    }
    int k = blockIdx.x * 256 + threadIdx.x;
    float v[DIM];
    const float4* p = reinterpret_cast<const float4*>(emb + (size_t)k * DIM);
#pragma unroll
    for (int i = 0; i < 16; ++i) {
        float4 a = p[i];
        v[4 * i + 0] = a.x; v[4 * i + 1] = a.y; v[4 * i + 2] = a.z; v[4 * i + 3] = a.w;
    }
    ee[k] = pairwise_sumsq64(v);
#pragma unroll
    for (int i = 0; i < 8; ++i) {
        half8 h;
#pragma unroll
        for (int j = 0; j < 8; ++j) h[j] = (_Float16)(v[8 * i + j] * 256.0f);
        *reinterpret_cast<half8*>(ehi + (size_t)k * DIM + 8 * i) = h;
    }
}

// top-4 insert in MAX domain: slots 1..3 carry ids, slot 4 is value-only guard.
#define INS4MAX(x, xid, s)                                    \
    {                                                         \
        bool q1 = (x) > M1[s], q2 = (x) > M2[s], q3 = (x) > M3[s]; \
        M4[s] = q3 ? M3[s] : fmaxf((x), M4[s]);               \
        M3[s] = q2 ? M2[s] : (q3 ? (x) : M3[s]);              \
        G3[s] = q2 ? G2[s] : (q3 ? (xid) : G3[s]);            \
        M2[s] = q1 ? M1[s] : (q2 ? (x) : M2[s]);              \
        G2[s] = q1 ? G1[s] : (q2 ? (xid) : G2[s]);            \
        M1[s] = q1 ? (x) : M1[s];                             \
        G1[s] = q1 ? (xid) : G1[s];                           \
    }

// Scan: per block 128 rows x one 2048-code half; 16 iterations of 128 codes.
// 3-deep pair-buffer ring (48 KB): iteration it waits vmcnt(4) (own pair-it
// loads retired; pair it+1 stays in flight), ONE raw s_barrier (also
// protects ring reuse: issue comes after it), issues pair it+2, computes
// pair it (2 sub-chunks, identical arithmetic/section ids to the old
// 64-code chunks cc = 2*it+sc).
__launch_bounds__(256, 4)
__global__ void vq_scan(const float* __restrict__ z, const _Float16* __restrict__ ehi,
                        float* __restrict__ tU1, int* __restrict__ tK1,
                        float* __restrict__ tU2, int* __restrict__ tK23,
                        float* __restrict__ tU3, float* __restrict__ tU4) {
    __shared__ float4 sB[3][1024];   // 3 x 16 KB pair-buffer ring

    const int tid = threadIdx.x;
    const int lane = tid & 63;
    const int w = tid >> 6;
    const int rlo = lane & 15;
    const int quad = lane >> 4;
    const int half = blockIdx.y;                 // 2 K-halves of 2048 codes
    const int rowbase = blockIdx.x * 128 + w * 32;   // 32 rows per wave

    // z fragments (B operand): 2 row-tiles x 2 k-slices, f16
    half8 zhi[2][2];
#pragma unroll
    for (int rt = 0; rt < 2; ++rt) {
        const float* zp = z + (size_t)(rowbase + rt * 16 + rlo) * DIM + quad * 8;
#pragma unroll
        for (int ks = 0; ks < 2; ++ks) {
            float4 a = *reinterpret_cast<const float4*>(zp + ks * 32);
            float4 b = *reinterpret_cast<const float4*>(zp + ks * 32 + 4);
            float f[8] = {a.x, a.y, a.z, a.w, b.x, b.y, b.z, b.w};
            half8 hi;
#pragma unroll
            for (int e = 0; e < 8; ++e) hi[e] = (_Float16)f[e];
            zhi[rt][ks] = hi;
        }
    }

    // Pre-swizzled source offsets for a 16KB PAIR (two consecutive 8KB chunks,
    // each with the proven slot map). LDS written LINEARLY (slot L = tid+i*256).
    int gOff[4];
#pragma unroll
    for (int i = 0; i < 4; ++i) {
        int L = tid + i * 256;               // 0..1023
        int ch = L >> 9;                     // which chunk of the pair
        int Lc = L & 511;
        int T = Lc >> 6, u = Lc & 63;
        int code = (T >> 1) * 16 + (u & 15);
        int dg = (T & 1) * 4 + (u >> 4);
        gOff[i] = ch * 8192 + (code * 8 + dg) * 16;
    }
    const char* srcHiB = (const char*)ehi + (size_t)half * 2048 * 128;

    auto issue = [&](int pr, int bb) {
        const char* hs = srcHiB + (size_t)pr * 16384;
        char* dH = (char*)&sB[bb][0];
#pragma unroll
        for (int i = 0; i < 4; ++i)
            gload_lds16(hs + gOff[i], dH + (tid + i * 256) * 16);
    };

    issue(0, 0);
    issue(1, 1);

    float M1[2], M2[2], M3[2], M4[2];
    int G1[2], G2[2], G3[2];
#pragma unroll
    for (int s = 0; s < 2; ++s) {
        M1[s] = -3e38f; M2[s] = -3e38f; M3[s] = -3e38f; M4[s] = -3e38f;
        G1[s] = 0; G2[s] = 0; G3[s] = 0;
    }
    const f32x4 zero4 = {0.f, 0.f, 0.f, 0.f};

#pragma unroll 1
    for (int it = 0; it < 16; ++it) {
        if (it < 15) {
            WAITVM(4);       // own pair-it loads retired (pair it+1 in flight)
        } else {
            WAITVM(0);
        }
        __builtin_amdgcn_s_barrier();    // all waves: pair-it staged AND
        __builtin_amdgcn_sched_barrier(0);  // prev compute done (ring safe)
        if (it < 14) issue(it + 2, (it + 2) % 3);

        const float4* bp = &sB[it % 3][0];
#pragma unroll
        for (int sc = 0; sc < 2; ++sc) {
            const float4* bh = bp + sc * 512;
            float run[2];
#pragma unroll
            for (int s = 0; s < 2; ++s) run[s] = -3e38f;
#pragma unroll
            for (int t = 0; t < 4; ++t) {
                half8 a0h = __builtin_bit_cast(half8, bh[(t * 2 + 0) * 64 + lane]);
                half8 a1h = __builtin_bit_cast(half8, bh[(t * 2 + 1) * 64 + lane]);
#pragma unroll
                for (int rt = 0; rt < 2; ++rt) {
                    f32x4 acc = __builtin_amdgcn_mfma_f32_16x16x32_f16(a0h, zhi[rt][0], zero4, 0, 0, 0);
                    acc = __builtin_amdgcn_mfma_f32_16x16x32_f16(a1h, zhi[rt][1], acc, 0, 0, 0);
                    run[rt] = fmaxf(run[rt],
                                    fmaxf(fmaxf(acc[0], acc[1]), fmaxf(acc[2], acc[3])));
                }
            }
            const int gb = (((it << 1) + sc) << 6) + (quad << 2);  // section base
#pragma unroll
            for (int s = 0; s < 2; ++s) INS4MAX(run[s], gb, s);
        }
        __builtin_amdgcn_sched_barrier(0);
    }

    // merge top-3 sections across the 4 quads of each row
#pragma unroll
    for (int s = 0; s < 2; ++s) {
#pragma unroll
        for (int d = 16; d < 64; d <<= 1) {
            float o1 = __shfl_xor(M1[s], d); int p1 = __shfl_xor(G1[s], d);
            float o2 = __shfl_xor(M2[s], d); int p2 = __shfl_xor(G2[s], d);
            float o3 = __shfl_xor(M3[s], d); int p3 = __shfl_xor(G3[s], d);
            float o4 = __shfl_xor(M4[s], d);
            INS4MAX(o1, p1, s);
            INS4MAX(o2, p2, s);
            INS4MAX(o3, p3, s);
            M4[s] = fmaxf(M4[s], o4);
        }
    }

    if (lane < 16) {
        const int hoff = half << 11;
#pragma unroll
        for (int s = 0; s < 2; ++s) {
            int grow = rowbase + s * 16 + lane;
            size_t idx = (size_t)half * NROWS + grow;
            tU1[idx] = M1[s] * -0.0078125f;      // u-domain (exact *2^-7)
            tU2[idx] = M2[s] * -0.0078125f;
            tU3[idx] = M3[s] * -0.0078125f;
            tU4[idx] = M4[s] * -0.0078125f;
            tK1[idx] = G1[s] + hoff;
            tK23[idx] = (G2[s] + hoff) | ((G3[s] + hoff) << 16);
        }
    }
}

// finish: 16 lanes per row (16 rows/block, grid 4096 -> TLP-saturated).
// Lane j resolves ONE code per candidate section: k = base + 16*(j>>2)+(j&3)
// — identical per-code arithmetic to the 1-thread version. Index-only output.
__global__ void vq_finish(const float* __restrict__ z, const float* __restrict__ emb,
                          const float* __restrict__ ee,
                          const float* __restrict__ tU1, const int* __restrict__ tK1,
                          const float* __restrict__ tU2, const int* __restrict__ tK23,
                          const float* __restrict__ tU3, const float* __restrict__ tU4,
                          float* __restrict__ out,
                          int* __restrict__ listB, int* __restrict__ cntB) {
    const int tid = threadIdx.x;
    const int grp = tid >> 4;       // row group within block
    const int j = tid & 15;         // lane role within row
    const int row = blockIdx.x * 16 + grp;

    // merge half tuples (redundant per lane; loads broadcast within group)
    float u1 = tU1[row]; int g1 = tK1[row];
    float u2 = tU2[row];
    float u3 = tU3[row]; float u4 = tU4[row];
    int k23 = tK23[row];
    int g2 = k23 & 0xFFFF, g3 = ((unsigned)k23) >> 16;
    {
        float b1 = tU1[NROWS + row]; int h1 = tK1[NROWS + row];
        float b2 = tU2[NROWS + row];
        float b3 = tU3[NROWS + row]; float b4 = tU4[NROWS + row];
        int hk = tK23[NROWS + row];
        int h2 = hk & 0xFFFF, h3 = ((unsigned)hk) >> 16;
#define INSU(bv, bi)                                           \
        { bool q1 = (bv) < u1, q2 = (bv) < u2, q3 = (bv) < u3; \
          u4 = q3 ? u3 : fminf((bv), u4);                      \
          u3 = q2 ? u2 : (q3 ? (bv) : u3);                     \
          g3 = q2 ? g2 : (q3 ? (bi) : g3);                     \
          u2 = q1 ? u1 : (q2 ? (bv) : u2);                     \
          g2 = q1 ? g1 : (q2 ? (bi) : g2);                     \
          u1 = q1 ? (bv) : u1;                                 \
          g1 = q1 ? (bi) : g1; }
        INSU(b1, h1);
        INSU(b2, h2);
        INSU(b3, h3);
        u4 = fminf(u4, b4);
#undef INSU
    }

    // load z row (explicit register array, float4 loads)
    float zr[DIM];
    {
        const float4* zp = reinterpret_cast<const float4*>(z + (size_t)row * DIM);
#pragma unroll
        for (int i = 0; i < 16; ++i) {
            float4 a = zp[i];
            zr[4 * i + 0] = a.x; zr[4 * i + 1] = a.y; zr[4 * i + 2] = a.z; zr[4 * i + 3] = a.w;
        }
    }
    float zzs = 0.f;
#pragma unroll
    for (int i = 0; i < DIM; ++i) zzs = fmaf(zr[i], zr[i], zzs);

    // threshold: ref f32 rounding (~2.2 ulp zz) + f16-screen error + ee drop
    float delta = ((zzs > 120.f) ? 3.4e-5f : 1.7e-5f) + 2.5e-5f;

    // 4th section within delta -> exact full scan resolves (and overwrites) later
    if (j == 0 && u4 - u1 < delta) {
        int p = atomicAdd(cntB, 1);
        listB[p] = row;
    }

    // exact resolve: lane j takes code base + 16*(j>>2) + (j&3) of each section
    const float zz = pairwise_sumsq64(zr);
    const int joff = ((j >> 2) << 4) + (j & 3);
    unsigned long long bestkey = ~0ull;
    int secs[3]; int nsec = 1; secs[0] = g1;
    if (u2 - u1 < delta) {
        secs[1] = g2; nsec = 2;
        if (u3 - u1 < delta) { secs[2] = g3; nsec = 3; }
    }
    for (int si = 0; si < nsec; ++si) {
        int k = secs[si] + joff;
        float d2 = exact_d2(emb, k, zr, zz, ee[k]);
        unsigned long long key =
            (((unsigned long long)__float_as_uint(d2)) << 32) | (unsigned)k;
        bestkey = key < bestkey ? key : bestkey;
    }
    {   // min over the 16 lanes of this row
#pragma unroll
        for (int d = 1; d < 16; d <<= 1) {
            unsigned long long o = __shfl_xor(bestkey, d);
            bestkey = o < bestkey ? o : bestkey;
        }
    }
    if (j == 0) out[OUT_IDX_OFF + row] = (float)(int)(bestkey & 0xFFFFFFFFu);
}

// emit: epilogue, fully coalesced. Per block: 64 rows. Stage z + chosen emb
// rows in LDS (stride-65 pad), write NCHW d-major (256B segments),
// rowloss + block loss partial.
__launch_bounds__(256, 4)
__global__ void vq_emit(const float* __restrict__ z, const float* __restrict__ emb,
                        float* __restrict__ out, float* __restrict__ rowloss,
                        double* __restrict__ part) {
    __shared__ float zs[64 * 65];
    __shared__ float qs[64 * 65];
    __shared__ float ls[64 * 5];
    const int tid = threadIdx.x;
    const int rl = tid >> 2;        // row within block
    const int j = tid & 3;          // quarter-row role
    const int row = blockIdx.x * 64 + rl;

    // stage z: thread tid loads its 64B chunk (fully coalesced), scalar LDS writes
    {
        const float4* zp = reinterpret_cast<const float4*>(
            z + (size_t)blockIdx.x * 4096 + (size_t)tid * 16);
        float4 a = zp[0], b = zp[1], c = zp[2], d = zp[3];
        float v[16] = {a.x, a.y, a.z, a.w, b.x, b.y, b.z, b.w,
                       c.x, c.y, c.z, c.w, d.x, d.y, d.z, d.w};
        float* dst = &zs[rl * 65 + j * 16];
#pragma unroll
        for (int i = 0; i < 16; ++i) dst[i] = v[i];
    }
    // stage chosen emb row (4-lane cooperative, 64B per lane)
    {
        const int kb = (int)out[OUT_IDX_OFF + row];
        const float4* qp = reinterpret_cast<const float4*>(
            emb + (size_t)kb * DIM + j * 16);
        float4 a = qp[0], b = qp[1], c = qp[2], d = qp[3];
        float v[16] = {a.x, a.y, a.z, a.w, b.x, b.y, b.z, b.w,
                       c.x, c.y, c.z, c.w, d.x, d.y, d.z, d.w};
        float* dst = &qs[rl * 65 + j * 16];
#pragma unroll
        for (int i = 0; i < 16; ++i) dst[i] = v[i];
    }
    __syncthreads();

    // write phase: wave w covers d in [16w, 16w+16); lanes = 64 consecutive hw
    const int hw_l = tid & 63;
    const int w = tid >> 6;
    const int bimg = row >> 12;
    const int hwb = (blockIdx.x * 64) & 4095;
    float* ob = out + (size_t)bimg * 262144 + hwb + hw_l;
    float lp = 0.f;
#pragma unroll
    for (int k = 0; k < 16; ++k) {
        const int d = w * 16 + k;
        float qv = qs[hw_l * 65 + d];
        float zv = zs[hw_l * 65 + d];
        float df = qv - zv;
        lp = fmaf(df, df, lp);
        ob[(size_t)d * 4096] = qv;
    }
    ls[hw_l * 5 + w] = lp;
    __syncthreads();

    // rowloss + block partial (wave 0)
    if (tid < 64) {
        float r01 = ls[tid * 5 + 0] + ls[tid * 5 + 1];
        float r23 = ls[tid * 5 + 2] + ls[tid * 5 + 3];
        float rsum = r01 + r23;
        rowloss[blockIdx.x * 64 + tid] = rsum;
        double s = (double)rsum;
#pragma unroll
        for (int d = 1; d < 64; d <<= 1) s += __shfl_xor(s, d);
        if (tid == 0) atomicAdd(&part[blockIdx.x >> 2], s);
    }
}

// exact full scan for rows with 4+ near-tied sections (block per row, grid-stride)
__global__ void vq_fallback(const float* __restrict__ z, const float* __restrict__ emb,
                            const float* __restrict__ ee, const int* __restrict__ listB,
                            const int* __restrict__ cntB, float* __restrict__ out,
                            const float* __restrict__ rowloss, double* __restrict__ part) {
    __shared__ float sZ[DIM];
    __shared__ unsigned long long sK[4];
    __shared__ int sKb;
    const int n = *cntB;
    const int tid = threadIdx.x;
    const int lane = tid & 63;
    const int w = tid >> 6;

    for (int i = blockIdx.x; i < n; i += 1024) {
        const int row = listB[i];
        __syncthreads();
        if (tid < DIM) sZ[tid] = z[(size_t)row * DIM + tid];
        __syncthreads();
        float zr[DIM];
#pragma unroll
        for (int q = 0; q < DIM; ++q) zr[q] = sZ[q];
        const float zz = pairwise_sumsq64(zr);

        unsigned long long best = ~0ull;
#pragma unroll 1
        for (int j = 0; j < 16; ++j) {
            int c = tid + j * 256;
            float d2 = exact_d2(emb, c, zr, zz, ee[c]);
            unsigned long long key =
                (((unsigned long long)__float_as_uint(d2)) << 32) | (unsigned)c;
            best = key < best ? key : best;
        }
#pragma unroll
        for (int d = 1; d < 64; d <<= 1) {
            unsigned long long o2 = __shfl_xor(best, d);
            best = o2 < best ? o2 : best;
        }
        if (lane == 0) sK[w] = best;
        __syncthreads();
        if (tid == 0) {
            unsigned long long b = sK[0];
            b = sK[1] < b ? sK[1] : b;
            b = sK[2] < b ? sK[2] : b;
            b = sK[3] < b ? sK[3] : b;
            sKb = (int)(b & 0xFFFFFFFFu);
        }
        __syncthreads();
        const int kb = sKb;
        if (tid < DIM) {
            const float qv = emb[(size_t)kb * DIM + tid];
            const float zv = sZ[tid];
            int bimg = row >> 12, hw = row & 4095;
            out[(size_t)bimg * 262144 + (size_t)tid * 4096 + hw] = qv;
            float lp = (qv - zv) * (qv - zv);
#pragma unroll
            for (int d = 1; d < 64; d <<= 1) lp += __shfl_xor(lp, d);
            if (tid == 0) {
                // adjust fused loss partials by the correction delta
                double dl = (double)lp - (double)rowloss[row];
                atomicAdd(&part[row >> 8], dl);
                out[OUT_IDX_OFF + row] = (float)kb;
            }
        }
    }
}

__global__ void vq_red2(const double* __restrict__ part, float* __restrict__ out_loss) {
    __shared__ double sd[256];
    sd[threadIdx.x] = part[threadIdx.x];
    __syncthreads();
    for (int st = 128; st > 0; st >>= 1) {
        if (threadIdx.x < st) sd[threadIdx.x] += sd[threadIdx.x + st];
        __syncthreads();
    }
    if (threadIdx.x == 0) out_loss[0] = (float)(0.25 * sd[0]);
}

extern "C" void kernel_launch(void* const* d_in, const int* in_sizes, int n_in,
                              void* d_out, int out_size, void* d_ws, size_t ws_size,
                              hipStream_t stream) {
    const float* z = (const float*)d_in[0];
    const float* emb = (const float*)d_in[1];
    float* out = (float*)d_out;
    char* ws = (char*)d_ws;

    _Float16* ehi = (_Float16*)(ws + WS_EHI);
    float* ee = (float*)(ws + WS_EE);
    float* rowloss = (float*)(ws + WS_RLOSS);
    float* tU1 = (float*)(ws + WS_TU1);
    int*   tK1 = (int*)(ws + WS_TK1);
    float* tU2 = (float*)(ws + WS_TU2);
    int*   tK23 = (int*)(ws + WS_TK23);
    float* tU3 = (float*)(ws + WS_TU3);
    float* tU4 = (float*)(ws + WS_TU4);
    int* listB = (int*)(ws + WS_LISTB);
    int* cntB  = (int*)(ws + WS_CNTB);
    double* part = (double*)(ws + WS_PART);

    vq_prep<<<NCODES / 256, 256, 0, stream>>>(emb, ehi, ee, cntB, part);
    vq_scan<<<dim3(NROWS / 128, 2), 256, 0, stream>>>(z, ehi, tU1, tK1, tU2, tK23, tU3, tU4);
    vq_finish<<<NROWS / 16, 256, 0, stream>>>(z, emb, ee, tU1, tK1, tU2, tK23, tU3, tU4,
                                              out, listB, cntB);
    vq_emit<<<NROWS / 64, 256, 0, stream>>>(z, emb, out, rowloss, part);
    vq_fallback<<<1024, 256, 0, stream>>>(z, emb, ee, listB, cntB, out, rowloss, part);
    vq_red2<<<1, 256, 0, stream>>>(part, out + OUT_LOSS_OFF);
}

// Round 14
// 173.781 us; speedup vs baseline: 1.0558x; 1.0558x over previous
//
#include <hip/hip_runtime.h>

// VQ-VAE quantizer eval forward — single-f16 MFMA screen (A=codes, B=z) with
// 16-code-section top-3 tracking + exact section resolve.
// Scan: 128 rows/block; 32 chunks of 64 codes, 4-buffer 8KB global_load_lds
// ring (32KB LDS, 4 blocks/CU), raw s_barrier + counted vmcnt — R12 version
// (65 µs measured; R13's 48KB pair-ring cut occupancy and regressed).
// Finish: 16-lane-per-row (1M threads). Emit: coalesced d-major epilogue.
// z: [16,64,64,64] f32 (N=65536 rows, D=64), emb: [4096,64] f32
// out: [quantized NCHW 4194304][indices 65536][loss 1] (all f32)

typedef _Float16 half8 __attribute__((ext_vector_type(8)));
typedef float f32x4 __attribute__((ext_vector_type(4)));

#define NCODES 4096
#define DIM 64
#define NROWS 65536
#define OUT_IDX_OFF 4194304
#define OUT_LOSS_OFF 4259840

// ws byte offsets (total ~4.2 MB)
#define WS_EHI   0u            // 4096*64 f16 = 512KB (emb*256)
#define WS_EE    524288u       // 4096 f32 exact sumsq
#define WS_RLOSS 540672u       // 65536 f32
#define WS_TU1   802816u       // [2][65536] f32 u1 (best section min-u est)
#define WS_TK1   1327104u      // [2][65536] int g1 (section base code)
#define WS_TU2   1851392u      // [2][65536] f32 u2
#define WS_TK23  2375680u      // [2][65536] int packed (g2 | g3<<16)
#define WS_TU3   2899968u      // [2][65536] f32 u3
#define WS_TU4   3424256u      // [2][65536] f32 u4 (4th section guard)
#define WS_LISTB 3948544u      // 65536 int
#define WS_CNTB  4210688u      // int
#define WS_PART  4210944u      // 256 f64

// exact numpy-pairwise sum of squares, n=64 (R1-verified)
__device__ __forceinline__ float pairwise_sumsq64(const float* v) {
    float r[8];
#pragma unroll
    for (int j = 0; j < 8; ++j) r[j] = __fmul_rn(v[j], v[j]);
#pragma unroll
    for (int m = 1; m < 8; ++m) {
#pragma unroll
        for (int j = 0; j < 8; ++j)
            r[j] = __fadd_rn(r[j], __fmul_rn(v[8 * m + j], v[8 * m + j]));
    }
    float s01 = __fadd_rn(r[0], r[1]);
    float s23 = __fadd_rn(r[2], r[3]);
    float s45 = __fadd_rn(r[4], r[5]);
    float s67 = __fadd_rn(r[6], r[7]);
    return __fadd_rn(__fadd_rn(s01, s23), __fadd_rn(s45, s67));
}

// exact ref d2 for code k (R1-verified semantics)
__device__ __forceinline__ float exact_d2(const float* __restrict__ emb, int k,
                                          const float* zr, float zz, float eev) {
    const float4* ep = reinterpret_cast<const float4*>(emb + (size_t)k * DIM);
    float da = 0.f;
#pragma unroll
    for (int q = 0; q < 16; ++q) {
        float4 A = ep[q];
        da += A.x * zr[4 * q + 0]; da += A.y * zr[4 * q + 1];
        da += A.z * zr[4 * q + 2]; da += A.w * zr[4 * q + 3];
    }
    return __fadd_rn(__fsub_rn(zz, __fmul_rn(2.0f, da)), eev);
}

// async global->LDS, 16B per lane (linear LDS dest; swizzle lives in the SOURCE addr)
__device__ __forceinline__ void gload_lds16(const void* g, void* l) {
    __builtin_amdgcn_global_load_lds(
        (const __attribute__((address_space(1))) unsigned int*)g,
        (__attribute__((address_space(3))) unsigned int*)l, 16, 0, 0);
}

#define WAITVM(n)                                               \
    {                                                           \
        asm volatile("s_waitcnt vmcnt(" #n ")" ::: "memory");   \
        __builtin_amdgcn_sched_barrier(0);                      \
    }

// prep also zeroes cntB/part (replaces two hipMemsetAsync dispatches)
__global__ void vq_prep(const float* __restrict__ emb, _Float16* __restrict__ ehi,
                        float* __restrict__ ee, int* __restrict__ cntB,
                        double* __restrict__ part) {
    if (blockIdx.x == 0) {
        part[threadIdx.x] = 0.0;
        if (threadIdx.x == 0) *cntB = 0;
    }
    int k = blockIdx.x * 256 + threadIdx.x;
    float v[DIM];
    const float4* p = reinterpret_cast<const float4*>(emb + (size_t)k * DIM);
#pragma unroll
    for (int i = 0; i < 16; ++i) {
        float4 a = p[i];
        v[4 * i + 0] = a.x; v[4 * i + 1] = a.y; v[4 * i + 2] = a.z; v[4 * i + 3] = a.w;
    }
    ee[k] = pairwise_sumsq64(v);
#pragma unroll
    for (int i = 0; i < 8; ++i) {
        half8 h;
#pragma unroll
        for (int j = 0; j < 8; ++j) h[j] = (_Float16)(v[8 * i + j] * 256.0f);
        *reinterpret_cast<half8*>(ehi + (size_t)k * DIM + 8 * i) = h;
    }
}

// top-4 insert in MAX domain: slots 1..3 carry ids, slot 4 is value-only guard.
#define INS4MAX(x, xid, s)                                    \
    {                                                         \
        bool q1 = (x) > M1[s], q2 = (x) > M2[s], q3 = (x) > M3[s]; \
        M4[s] = q3 ? M3[s] : fmaxf((x), M4[s]);               \
        M3[s] = q2 ? M2[s] : (q3 ? (x) : M3[s]);              \
        G3[s] = q2 ? G2[s] : (q3 ? (xid) : G3[s]);            \
        M2[s] = q1 ? M1[s] : (q2 ? (x) : M2[s]);              \
        G2[s] = q1 ? G1[s] : (q2 ? (xid) : G2[s]);            \
        M1[s] = q1 ? (x) : M1[s];                             \
        G1[s] = q1 ? (xid) : G1[s];                           \
    }

// Scan (R12 version): per block 128 rows x one 2048-code half; 32 chunks of
// 64 codes. 4-deep staging ring: body c issues chunk c+2, waits vmcnt(4)
// (own chunk-c loads retired; c+1/c+2 stay in flight), raw s_barrier,
// computes chunk c.
__launch_bounds__(256, 4)
__global__ void vq_scan(const float* __restrict__ z, const _Float16* __restrict__ ehi,
                        float* __restrict__ tU1, int* __restrict__ tK1,
                        float* __restrict__ tU2, int* __restrict__ tK23,
                        float* __restrict__ tU3, float* __restrict__ tU4) {
    __shared__ float4 sB[4][512];   // 4 x 8 KB staging ring

    const int tid = threadIdx.x;
    const int lane = tid & 63;
    const int w = tid >> 6;
    const int rlo = lane & 15;
    const int quad = lane >> 4;
    const int half = blockIdx.y;                 // 2 K-halves of 2048 codes
    const int rowbase = blockIdx.x * 128 + w * 32;   // 32 rows per wave

    // z fragments (B operand): 2 row-tiles x 2 k-slices, f16
    half8 zhi[2][2];
#pragma unroll
    for (int rt = 0; rt < 2; ++rt) {
        const float* zp = z + (size_t)(rowbase + rt * 16 + rlo) * DIM + quad * 8;
#pragma unroll
        for (int ks = 0; ks < 2; ++ks) {
            float4 a = *reinterpret_cast<const float4*>(zp + ks * 32);
            float4 b = *reinterpret_cast<const float4*>(zp + ks * 32 + 4);
            float f[8] = {a.x, a.y, a.z, a.w, b.x, b.y, b.z, b.w};
            half8 hi;
#pragma unroll
            for (int e = 0; e < 8; ++e) hi[e] = (_Float16)f[e];
            zhi[rt][ks] = hi;
        }
    }

    // Pre-swizzled source offsets: LDS written LINEARLY (slot L = tid + i*256);
    // slot L=T*64+u holds global float4 g = code*8+dg, code=(T>>1)*16+(u&15),
    // dg=(T&1)*4+(u>>4).
    int gOff[2];
#pragma unroll
    for (int i = 0; i < 2; ++i) {
        int L = tid + i * 256;
        int T = L >> 6, u = L & 63;
        int code = (T >> 1) * 16 + (u & 15);
        int dg = (T & 1) * 4 + (u >> 4);
        gOff[i] = (code * 8 + dg) * 16;          // byte offset within 8 KB chunk
    }
    const char* srcHiB = (const char*)ehi + (size_t)half * 2048 * 128;

    auto issue = [&](int cc, int bb) {
        const char* hs = srcHiB + (size_t)cc * 8192;
        char* dH = (char*)&sB[bb][0];
#pragma unroll
        for (int i = 0; i < 2; ++i)
            gload_lds16(hs + gOff[i], dH + (tid + i * 256) * 16);
    };

    issue(0, 0);
    issue(1, 1);

    float M1[2], M2[2], M3[2], M4[2];
    int G1[2], G2[2], G3[2];
#pragma unroll
    for (int s = 0; s < 2; ++s) {
        M1[s] = -3e38f; M2[s] = -3e38f; M3[s] = -3e38f; M4[s] = -3e38f;
        G1[s] = 0; G2[s] = 0; G3[s] = 0;
    }
    const f32x4 zero4 = {0.f, 0.f, 0.f, 0.f};

#pragma unroll 1
    for (int c = 0; c < 32; ++c) {
        if (c < 30) {
            issue(c + 2, (c + 2) & 3);   // 2-ahead prefetch, stays in flight
            WAITVM(4);                   // own chunk-c loads retired (FIFO)
        } else if (c == 30) {
            WAITVM(2);
        } else {
            WAITVM(0);
        }
        __builtin_amdgcn_s_barrier();    // raw: does NOT drain vmcnt
        __builtin_amdgcn_sched_barrier(0);

        const float4* bh = sB[c & 3];
        float run[2];
#pragma unroll
        for (int s = 0; s < 2; ++s) run[s] = -3e38f;
#pragma unroll
        for (int t = 0; t < 4; ++t) {
            half8 a0h = __builtin_bit_cast(half8, bh[(t * 2 + 0) * 64 + lane]);
            half8 a1h = __builtin_bit_cast(half8, bh[(t * 2 + 1) * 64 + lane]);
#pragma unroll
            for (int rt = 0; rt < 2; ++rt) {
                f32x4 acc = __builtin_amdgcn_mfma_f32_16x16x32_f16(a0h, zhi[rt][0], zero4, 0, 0, 0);
                acc = __builtin_amdgcn_mfma_f32_16x16x32_f16(a1h, zhi[rt][1], acc, 0, 0, 0);
                run[rt] = fmaxf(run[rt],
                                fmaxf(fmaxf(acc[0], acc[1]), fmaxf(acc[2], acc[3])));
            }
        }
        const int gb = (c << 6) + (quad << 2);   // section base (local to half)
#pragma unroll
        for (int s = 0; s < 2; ++s) INS4MAX(run[s], gb, s);
        __builtin_amdgcn_sched_barrier(0);
    }

    // merge top-3 sections across the 4 quads of each row
#pragma unroll
    for (int s = 0; s < 2; ++s) {
#pragma unroll
        for (int d = 16; d < 64; d <<= 1) {
            float o1 = __shfl_xor(M1[s], d); int p1 = __shfl_xor(G1[s], d);
            float o2 = __shfl_xor(M2[s], d); int p2 = __shfl_xor(G2[s], d);
            float o3 = __shfl_xor(M3[s], d); int p3 = __shfl_xor(G3[s], d);
            float o4 = __shfl_xor(M4[s], d);
            INS4MAX(o1, p1, s);
            INS4MAX(o2, p2, s);
            INS4MAX(o3, p3, s);
            M4[s] = fmaxf(M4[s], o4);
        }
    }

    if (lane < 16) {
        const int hoff = half << 11;
#pragma unroll
        for (int s = 0; s < 2; ++s) {
            int grow = rowbase + s * 16 + lane;
            size_t idx = (size_t)half * NROWS + grow;
            tU1[idx] = M1[s] * -0.0078125f;      // u-domain (exact *2^-7)
            tU2[idx] = M2[s] * -0.0078125f;
            tU3[idx] = M3[s] * -0.0078125f;
            tU4[idx] = M4[s] * -0.0078125f;
            tK1[idx] = G1[s] + hoff;
            tK23[idx] = (G2[s] + hoff) | ((G3[s] + hoff) << 16);
        }
    }
}

// finish: 16 lanes per row (16 rows/block, grid 4096 -> TLP-saturated).
// Lane j resolves ONE code per candidate section: k = base + 16*(j>>2)+(j&3)
// — identical per-code arithmetic to the 1-thread version. Index-only output.
__global__ void vq_finish(const float* __restrict__ z, const float* __restrict__ emb,
                          const float* __restrict__ ee,
                          const float* __restrict__ tU1, const int* __restrict__ tK1,
                          const float* __restrict__ tU2, const int* __restrict__ tK23,
                          const float* __restrict__ tU3, const float* __restrict__ tU4,
                          float* __restrict__ out,
                          int* __restrict__ listB, int* __restrict__ cntB) {
    const int tid = threadIdx.x;
    const int grp = tid >> 4;       // row group within block
    const int j = tid & 15;         // lane role within row
    const int row = blockIdx.x * 16 + grp;

    // merge half tuples (redundant per lane; loads broadcast within group)
    float u1 = tU1[row]; int g1 = tK1[row];
    float u2 = tU2[row];
    float u3 = tU3[row]; float u4 = tU4[row];
    int k23 = tK23[row];
    int g2 = k23 & 0xFFFF, g3 = ((unsigned)k23) >> 16;
    {
        float b1 = tU1[NROWS + row]; int h1 = tK1[NROWS + row];
        float b2 = tU2[NROWS + row];
        float b3 = tU3[NROWS + row]; float b4 = tU4[NROWS + row];
        int hk = tK23[NROWS + row];
        int h2 = hk & 0xFFFF, h3 = ((unsigned)hk) >> 16;
#define INSU(bv, bi)                                           \
        { bool q1 = (bv) < u1, q2 = (bv) < u2, q3 = (bv) < u3; \
          u4 = q3 ? u3 : fminf((bv), u4);                      \
          u3 = q2 ? u2 : (q3 ? (bv) : u3);                     \
          g3 = q2 ? g2 : (q3 ? (bi) : g3);                     \
          u2 = q1 ? u1 : (q2 ? (bv) : u2);                     \
          g2 = q1 ? g1 : (q2 ? (bi) : g2);                     \
          u1 = q1 ? (bv) : u1;                                 \
          g1 = q1 ? (bi) : g1; }
        INSU(b1, h1);
        INSU(b2, h2);
        INSU(b3, h3);
        u4 = fminf(u4, b4);
#undef INSU
    }

    // load z row (explicit register array, float4 loads)
    float zr[DIM];
    {
        const float4* zp = reinterpret_cast<const float4*>(z + (size_t)row * DIM);
#pragma unroll
        for (int i = 0; i < 16; ++i) {
            float4 a = zp[i];
            zr[4 * i + 0] = a.x; zr[4 * i + 1] = a.y; zr[4 * i + 2] = a.z; zr[4 * i + 3] = a.w;
        }
    }
    float zzs = 0.f;
#pragma unroll
    for (int i = 0; i < DIM; ++i) zzs = fmaf(zr[i], zr[i], zzs);

    // threshold: ref f32 rounding (~2.2 ulp zz) + f16-screen error + ee drop
    float delta = ((zzs > 120.f) ? 3.4e-5f : 1.7e-5f) + 2.5e-5f;

    // 4th section within delta -> exact full scan resolves (and overwrites) later
    if (j == 0 && u4 - u1 < delta) {
        int p = atomicAdd(cntB, 1);
        listB[p] = row;
    }

    // exact resolve: lane j takes code base + 16*(j>>2) + (j&3) of each section
    const float zz = pairwise_sumsq64(zr);
    const int joff = ((j >> 2) << 4) + (j & 3);
    unsigned long long bestkey = ~0ull;
    int secs[3]; int nsec = 1; secs[0] = g1;
    if (u2 - u1 < delta) {
        secs[1] = g2; nsec = 2;
        if (u3 - u1 < delta) { secs[2] = g3; nsec = 3; }
    }
    for (int si = 0; si < nsec; ++si) {
        int k = secs[si] + joff;
        float d2 = exact_d2(emb, k, zr, zz, ee[k]);
        unsigned long long key =
            (((unsigned long long)__float_as_uint(d2)) << 32) | (unsigned)k;
        bestkey = key < bestkey ? key : bestkey;
    }
    {   // min over the 16 lanes of this row
#pragma unroll
        for (int d = 1; d < 16; d <<= 1) {
            unsigned long long o = __shfl_xor(bestkey, d);
            bestkey = o < bestkey ? o : bestkey;
        }
    }
    if (j == 0) out[OUT_IDX_OFF + row] = (float)(int)(bestkey & 0xFFFFFFFFu);
}

// emit: epilogue, fully coalesced. Per block: 64 rows. Stage z + chosen emb
// rows in LDS (stride-65 pad), write NCHW d-major (256B segments),
// rowloss + block loss partial.
__launch_bounds__(256, 4)
__global__ void vq_emit(const float* __restrict__ z, const float* __restrict__ emb,
                        float* __restrict__ out, float* __restrict__ rowloss,
                        double* __restrict__ part) {
    __shared__ float zs[64 * 65];
    __shared__ float qs[64 * 65];
    __shared__ float ls[64 * 5];
    const int tid = threadIdx.x;
    const int rl = tid >> 2;        // row within block
    const int j = tid & 3;          // quarter-row role
    const int row = blockIdx.x * 64 + rl;

    // stage z: thread tid loads its 64B chunk (fully coalesced), scalar LDS writes
    {
        const float4* zp = reinterpret_cast<const float4*>(
            z + (size_t)blockIdx.x * 4096 + (size_t)tid * 16);
        float4 a = zp[0], b = zp[1], c = zp[2], d = zp[3];
        float v[16] = {a.x, a.y, a.z, a.w, b.x, b.y, b.z, b.w,
                       c.x, c.y, c.z, c.w, d.x, d.y, d.z, d.w};
        float* dst = &zs[rl * 65 + j * 16];
#pragma unroll
        for (int i = 0; i < 16; ++i) dst[i] = v[i];
    }
    // stage chosen emb row (4-lane cooperative, 64B per lane)
    {
        const int kb = (int)out[OUT_IDX_OFF + row];
        const float4* qp = reinterpret_cast<const float4*>(
            emb + (size_t)kb * DIM + j * 16);
        float4 a = qp[0], b = qp[1], c = qp[2], d = qp[3];
        float v[16] = {a.x, a.y, a.z, a.w, b.x, b.y, b.z, b.w,
                       c.x, c.y, c.z, c.w, d.x, d.y, d.z, d.w};
        float* dst = &qs[rl * 65 + j * 16];
#pragma unroll
        for (int i = 0; i < 16; ++i) dst[i] = v[i];
    }
    __syncthreads();

    // write phase: wave w covers d in [16w, 16w+16); lanes = 64 consecutive hw
    const int hw_l = tid & 63;
    const int w = tid >> 6;
    const int bimg = row >> 12;
    const int hwb = (blockIdx.x * 64) & 4095;
    float* ob = out + (size_t)bimg * 262144 + hwb + hw_l;
    float lp = 0.f;
#pragma unroll
    for (int k = 0; k < 16; ++k) {
        const int d = w * 16 + k;
        float qv = qs[hw_l * 65 + d];
        float zv = zs[hw_l * 65 + d];
        float df = qv - zv;
        lp = fmaf(df, df, lp);
        ob[(size_t)d * 4096] = qv;
    }
    ls[hw_l * 5 + w] = lp;
    __syncthreads();

    // rowloss + block partial (wave 0)
    if (tid < 64) {
        float r01 = ls[tid * 5 + 0] + ls[tid * 5 + 1];
        float r23 = ls[tid * 5 + 2] + ls[tid * 5 + 3];
        float rsum = r01 + r23;
        rowloss[blockIdx.x * 64 + tid] = rsum;
        double s = (double)rsum;
#pragma unroll
        for (int d = 1; d < 64; d <<= 1) s += __shfl_xor(s, d);
        if (tid == 0) atomicAdd(&part[blockIdx.x >> 2], s);
    }
}

// exact full scan for rows with 4+ near-tied sections (block per row, grid-stride)
__global__ void vq_fallback(const float* __restrict__ z, const float* __restrict__ emb,
                            const float* __restrict__ ee, const int* __restrict__ listB,
                            const int* __restrict__ cntB, float* __restrict__ out,
                            const float* __restrict__ rowloss, double* __restrict__ part) {
    __shared__ float sZ[DIM];
    __shared__ unsigned long long sK[4];
    __shared__ int sKb;
    const int n = *cntB;
    const int tid = threadIdx.x;
    const int lane = tid & 63;
    const int w = tid >> 6;

    for (int i = blockIdx.x; i < n; i += 1024) {
        const int row = listB[i];
        __syncthreads();
        if (tid < DIM) sZ[tid] = z[(size_t)row * DIM + tid];
        __syncthreads();
        float zr[DIM];
#pragma unroll
        for (int q = 0; q < DIM; ++q) zr[q] = sZ[q];
        const float zz = pairwise_sumsq64(zr);

        unsigned long long best = ~0ull;
#pragma unroll 1
        for (int j = 0; j < 16; ++j) {
            int c = tid + j * 256;
            float d2 = exact_d2(emb, c, zr, zz, ee[c]);
            unsigned long long key =
                (((unsigned long long)__float_as_uint(d2)) << 32) | (unsigned)c;
            best = key < best ? key : best;
        }
#pragma unroll
        for (int d = 1; d < 64; d <<= 1) {
            unsigned long long o2 = __shfl_xor(best, d);
            best = o2 < best ? o2 : best;
        }
        if (lane == 0) sK[w] = best;
        __syncthreads();
        if (tid == 0) {
            unsigned long long b = sK[0];
            b = sK[1] < b ? sK[1] : b;
            b = sK[2] < b ? sK[2] : b;
            b = sK[3] < b ? sK[3] : b;
            sKb = (int)(b & 0xFFFFFFFFu);
        }
        __syncthreads();
        const int kb = sKb;
        if (tid < DIM) {
            const float qv = emb[(size_t)kb * DIM + tid];
            const float zv = sZ[tid];
            int bimg = row >> 12, hw = row & 4095;
            out[(size_t)bimg * 262144 + (size_t)tid * 4096 + hw] = qv;
            float lp = (qv - zv) * (qv - zv);
#pragma unroll
            for (int d = 1; d < 64; d <<= 1) lp += __shfl_xor(lp, d);
            if (tid == 0) {
                // adjust fused loss partials by the correction delta
                double dl = (double)lp - (double)rowloss[row];
                atomicAdd(&part[row >> 8], dl);
                out[OUT_IDX_OFF + row] = (float)kb;
            }
        }
    }
}

__global__ void vq_red2(const double* __restrict__ part, float* __restrict__ out_loss) {
    __shared__ double sd[256];
    sd[threadIdx.x] = part[threadIdx.x];
    __syncthreads();
    for (int st = 128; st > 0; st >>= 1) {
        if (threadIdx.x < st) sd[threadIdx.x] += sd[threadIdx.x + st];
        __syncthreads();
    }
    if (threadIdx.x == 0) out_loss[0] = (float)(0.25 * sd[0]);
}

extern "C" void kernel_launch(void* const* d_in, const int* in_sizes, int n_in,
                              void* d_out, int out_size, void* d_ws, size_t ws_size,
                              hipStream_t stream) {
    const float* z = (const float*)d_in[0];
    const float* emb = (const float*)d_in[1];
    float* out = (float*)d_out;
    char* ws = (char*)d_ws;

    _Float16* ehi = (_Float16*)(ws + WS_EHI);
    float* ee = (float*)(ws + WS_EE);
    float* rowloss = (float*)(ws + WS_RLOSS);
    float* tU1 = (float*)(ws + WS_TU1);
    int*   tK1 = (int*)(ws + WS_TK1);
    float* tU2 = (float*)(ws + WS_TU2);
    int*   tK23 = (int*)(ws + WS_TK23);
    float* tU3 = (float*)(ws + WS_TU3);
    float* tU4 = (float*)(ws + WS_TU4);
    int* listB = (int*)(ws + WS_LISTB);
    int* cntB  = (int*)(ws + WS_CNTB);
    double* part = (double*)(ws + WS_PART);

    vq_prep<<<NCODES / 256, 256, 0, stream>>>(emb, ehi, ee, cntB, part);
    vq_scan<<<dim3(NROWS / 128, 2), 256, 0, stream>>>(z, ehi, tU1, tK1, tU2, tK23, tU3, tU4);
    vq_finish<<<NROWS / 16, 256, 0, stream>>>(z, emb, ee, tU1, tK1, tU2, tK23, tU3, tU4,
                                              out, listB, cntB);
    vq_emit<<<NROWS / 64, 256, 0, stream>>>(z, emb, out, rowloss, part);
    vq_fallback<<<1024, 256, 0, stream>>>(z, emb, ee, listB, cntB, out, rowloss, part);
    vq_red2<<<1, 256, 0, stream>>>(part, out + OUT_LOSS_OFF);
}

// Round 15
// 169.090 us; speedup vs baseline: 1.0851x; 1.0277x over previous
//
#include <hip/hip_runtime.h>

// VQ-VAE quantizer eval forward — single-f16 MFMA screen (A=codes, B=z) with
// 16-code-section top-3 tracking + exact section resolve.
// Scan: 128 rows/block; 16 iterations x chunk-PAIRS over the SAME 4x8KB ring
// (32KB LDS, 4 blocks/CU — R13's regression was the 48KB ring, not pairing):
// barrier -> issue other-pair -> vmcnt(4) -> compute 2 chunks. 16 barriers.
// Finish: 16-lane-per-row (1M threads). Emit: coalesced d-major epilogue.
// z: [16,64,64,64] f32 (N=65536 rows, D=64), emb: [4096,64] f32
// out: [quantized NCHW 4194304][indices 65536][loss 1] (all f32)

typedef _Float16 half8 __attribute__((ext_vector_type(8)));
typedef float f32x4 __attribute__((ext_vector_type(4)));

#define NCODES 4096
#define DIM 64
#define NROWS 65536
#define OUT_IDX_OFF 4194304
#define OUT_LOSS_OFF 4259840

// ws byte offsets (total ~4.2 MB)
#define WS_EHI   0u            // 4096*64 f16 = 512KB (emb*256)
#define WS_EE    524288u       // 4096 f32 exact sumsq
#define WS_RLOSS 540672u       // 65536 f32
#define WS_TU1   802816u       // [2][65536] f32 u1 (best section min-u est)
#define WS_TK1   1327104u      // [2][65536] int g1 (section base code)
#define WS_TU2   1851392u      // [2][65536] f32 u2
#define WS_TK23  2375680u      // [2][65536] int packed (g2 | g3<<16)
#define WS_TU3   2899968u      // [2][65536] f32 u3
#define WS_TU4   3424256u      // [2][65536] f32 u4 (4th section guard)
#define WS_LISTB 3948544u      // 65536 int
#define WS_CNTB  4210688u      // int
#define WS_PART  4210944u      // 256 f64

// exact numpy-pairwise sum of squares, n=64 (R1-verified)
__device__ __forceinline__ float pairwise_sumsq64(const float* v) {
    float r[8];
#pragma unroll
    for (int j = 0; j < 8; ++j) r[j] = __fmul_rn(v[j], v[j]);
#pragma unroll
    for (int m = 1; m < 8; ++m) {
#pragma unroll
        for (int j = 0; j < 8; ++j)
            r[j] = __fadd_rn(r[j], __fmul_rn(v[8 * m + j], v[8 * m + j]));
    }
    float s01 = __fadd_rn(r[0], r[1]);
    float s23 = __fadd_rn(r[2], r[3]);
    float s45 = __fadd_rn(r[4], r[5]);
    float s67 = __fadd_rn(r[6], r[7]);
    return __fadd_rn(__fadd_rn(s01, s23), __fadd_rn(s45, s67));
}

// exact ref d2 for code k (R1-verified semantics)
__device__ __forceinline__ float exact_d2(const float* __restrict__ emb, int k,
                                          const float* zr, float zz, float eev) {
    const float4* ep = reinterpret_cast<const float4*>(emb + (size_t)k * DIM);
    float da = 0.f;
#pragma unroll
    for (int q = 0; q < 16; ++q) {
        float4 A = ep[q];
        da += A.x * zr[4 * q + 0]; da += A.y * zr[4 * q + 1];
        da += A.z * zr[4 * q + 2]; da += A.w * zr[4 * q + 3];
    }
    return __fadd_rn(__fsub_rn(zz, __fmul_rn(2.0f, da)), eev);
}

// async global->LDS, 16B per lane (linear LDS dest; swizzle lives in the SOURCE addr)
__device__ __forceinline__ void gload_lds16(const void* g, void* l) {
    __builtin_amdgcn_global_load_lds(
        (const __attribute__((address_space(1))) unsigned int*)g,
        (__attribute__((address_space(3))) unsigned int*)l, 16, 0, 0);
}

#define WAITVM(n)                                               \
    {                                                           \
        asm volatile("s_waitcnt vmcnt(" #n ")" ::: "memory");   \
        __builtin_amdgcn_sched_barrier(0);                      \
    }

// prep also zeroes cntB/part (replaces two hipMemsetAsync dispatches)
__global__ void vq_prep(const float* __restrict__ emb, _Float16* __restrict__ ehi,
                        float* __restrict__ ee, int* __restrict__ cntB,
                        double* __restrict__ part) {
    if (blockIdx.x == 0) {
        part[threadIdx.x] = 0.0;
        if (threadIdx.x == 0) *cntB = 0;
    }
    int k = blockIdx.x * 256 + threadIdx.x;
    float v[DIM];
    const float4* p = reinterpret_cast<const float4*>(emb + (size_t)k * DIM);
#pragma unroll
    for (int i = 0; i < 16; ++i) {
        float4 a = p[i];
        v[4 * i + 0] = a.x; v[4 * i + 1] = a.y; v[4 * i + 2] = a.z; v[4 * i + 3] = a.w;
    }
    ee[k] = pairwise_sumsq64(v);
#pragma unroll
    for (int i = 0; i < 8; ++i) {
        half8 h;
#pragma unroll
        for (int j = 0; j < 8; ++j) h[j] = (_Float16)(v[8 * i + j] * 256.0f);
        *reinterpret_cast<half8*>(ehi + (size_t)k * DIM + 8 * i) = h;
    }
}

// top-4 insert in MAX domain: slots 1..3 carry ids, slot 4 is value-only guard.
#define INS4MAX(x, xid, s)                                    \
    {                                                         \
        bool q1 = (x) > M1[s], q2 = (x) > M2[s], q3 = (x) > M3[s]; \
        M4[s] = q3 ? M3[s] : fmaxf((x), M4[s]);               \
        M3[s] = q2 ? M2[s] : (q3 ? (x) : M3[s]);              \
        G3[s] = q2 ? G2[s] : (q3 ? (xid) : G3[s]);            \
        M2[s] = q1 ? M1[s] : (q2 ? (x) : M2[s]);              \
        G2[s] = q1 ? G1[s] : (q2 ? (xid) : G2[s]);            \
        M1[s] = q1 ? (x) : M1[s];                             \
        G1[s] = q1 ? (xid) : G1[s];                           \
    }

// Scan: per block 128 rows x one 2048-code half; 16 iterations of chunk-pairs
// over the SAME 4x8KB ring as R12/R14. Iteration p:
//   s_barrier            (all waves done pair p-1 -> opposite buffer-pair free)
//   issue pair p+1       (into opposite pair: parity(p+1) != parity(p))
//   vmcnt(4)             (pair p retired; pair p+1 stays in flight — FIFO)
//   compute chunks 2p, 2p+1
// Half the barriers of R12 at identical LDS/occupancy.
__launch_bounds__(256, 4)
__global__ void vq_scan(const float* __restrict__ z, const _Float16* __restrict__ ehi,
                        float* __restrict__ tU1, int* __restrict__ tK1,
                        float* __restrict__ tU2, int* __restrict__ tK23,
                        float* __restrict__ tU3, float* __restrict__ tU4) {
    __shared__ float4 sB[4][512];   // 4 x 8 KB ring (two buffer-pairs)

    const int tid = threadIdx.x;
    const int lane = tid & 63;
    const int w = tid >> 6;
    const int rlo = lane & 15;
    const int quad = lane >> 4;
    const int half = blockIdx.y;                 // 2 K-halves of 2048 codes
    const int rowbase = blockIdx.x * 128 + w * 32;   // 32 rows per wave

    // z fragments (B operand): 2 row-tiles x 2 k-slices, f16
    half8 zhi[2][2];
#pragma unroll
    for (int rt = 0; rt < 2; ++rt) {
        const float* zp = z + (size_t)(rowbase + rt * 16 + rlo) * DIM + quad * 8;
#pragma unroll
        for (int ks = 0; ks < 2; ++ks) {
            float4 a = *reinterpret_cast<const float4*>(zp + ks * 32);
            float4 b = *reinterpret_cast<const float4*>(zp + ks * 32 + 4);
            float f[8] = {a.x, a.y, a.z, a.w, b.x, b.y, b.z, b.w};
            half8 hi;
#pragma unroll
            for (int e = 0; e < 8; ++e) hi[e] = (_Float16)f[e];
            zhi[rt][ks] = hi;
        }
    }

    // Pre-swizzled source offsets: LDS written LINEARLY (slot L = tid + i*256);
    // slot L=T*64+u holds global float4 g = code*8+dg, code=(T>>1)*16+(u&15),
    // dg=(T&1)*4+(u>>4).
    int gOff[2];
#pragma unroll
    for (int i = 0; i < 2; ++i) {
        int L = tid + i * 256;
        int T = L >> 6, u = L & 63;
        int code = (T >> 1) * 16 + (u & 15);
        int dg = (T & 1) * 4 + (u >> 4);
        gOff[i] = (code * 8 + dg) * 16;          // byte offset within 8 KB chunk
    }
    const char* srcHiB = (const char*)ehi + (size_t)half * 2048 * 128;

    auto issue = [&](int cc, int bb) {
        const char* hs = srcHiB + (size_t)cc * 8192;
        char* dH = (char*)&sB[bb][0];
#pragma unroll
        for (int i = 0; i < 2; ++i)
            gload_lds16(hs + gOff[i], dH + (tid + i * 256) * 16);
    };

    issue(0, 0);   // pair 0 -> buffers {0,1}
    issue(1, 1);

    float M1[2], M2[2], M3[2], M4[2];
    int G1[2], G2[2], G3[2];
#pragma unroll
    for (int s = 0; s < 2; ++s) {
        M1[s] = -3e38f; M2[s] = -3e38f; M3[s] = -3e38f; M4[s] = -3e38f;
        G1[s] = 0; G2[s] = 0; G3[s] = 0;
    }
    const f32x4 zero4 = {0.f, 0.f, 0.f, 0.f};

#pragma unroll 1
    for (int p = 0; p < 16; ++p) {
        __builtin_amdgcn_s_barrier();    // raw: all waves done pair p-1
        __builtin_amdgcn_sched_barrier(0);
        if (p < 15) {                    // issue pair p+1 into opposite buffers
            issue(2 * p + 2, (2 * p + 2) & 3);
            issue(2 * p + 3, (2 * p + 3) & 3);
            WAITVM(4);                   // pair p retired; p+1 stays in flight
        } else {
            WAITVM(0);
        }

#pragma unroll
        for (int sc = 0; sc < 2; ++sc) {
            const int c = 2 * p + sc;
            const float4* bh = sB[c & 3];
            float run[2];
#pragma unroll
            for (int s = 0; s < 2; ++s) run[s] = -3e38f;
#pragma unroll
            for (int t = 0; t < 4; ++t) {
                half8 a0h = __builtin_bit_cast(half8, bh[(t * 2 + 0) * 64 + lane]);
                half8 a1h = __builtin_bit_cast(half8, bh[(t * 2 + 1) * 64 + lane]);
#pragma unroll
                for (int rt = 0; rt < 2; ++rt) {
                    f32x4 acc = __builtin_amdgcn_mfma_f32_16x16x32_f16(a0h, zhi[rt][0], zero4, 0, 0, 0);
                    acc = __builtin_amdgcn_mfma_f32_16x16x32_f16(a1h, zhi[rt][1], acc, 0, 0, 0);
                    // max3-shaped tree: clang fuses fmaxf(fmaxf(a,b),c) -> v_max3_f32
                    float t1 = fmaxf(fmaxf(acc[0], acc[1]), acc[2]);
                    run[rt] = fmaxf(fmaxf(t1, acc[3]), run[rt]);
                }
            }
            const int gb = (c << 6) + (quad << 2);   // section base (local to half)
#pragma unroll
            for (int s = 0; s < 2; ++s) INS4MAX(run[s], gb, s);
        }
        __builtin_amdgcn_sched_barrier(0);
    }

    // merge top-3 sections across the 4 quads of each row
#pragma unroll
    for (int s = 0; s < 2; ++s) {
#pragma unroll
        for (int d = 16; d < 64; d <<= 1) {
            float o1 = __shfl_xor(M1[s], d); int p1 = __shfl_xor(G1[s], d);
            float o2 = __shfl_xor(M2[s], d); int p2 = __shfl_xor(G2[s], d);
            float o3 = __shfl_xor(M3[s], d); int p3 = __shfl_xor(G3[s], d);
            float o4 = __shfl_xor(M4[s], d);
            INS4MAX(o1, p1, s);
            INS4MAX(o2, p2, s);
            INS4MAX(o3, p3, s);
            M4[s] = fmaxf(M4[s], o4);
        }
    }

    if (lane < 16) {
        const int hoff = half << 11;
#pragma unroll
        for (int s = 0; s < 2; ++s) {
            int grow = rowbase + s * 16 + lane;
            size_t idx = (size_t)half * NROWS + grow;
            tU1[idx] = M1[s] * -0.0078125f;      // u-domain (exact *2^-7)
            tU2[idx] = M2[s] * -0.0078125f;
            tU3[idx] = M3[s] * -0.0078125f;
            tU4[idx] = M4[s] * -0.0078125f;
            tK1[idx] = G1[s] + hoff;
            tK23[idx] = (G2[s] + hoff) | ((G3[s] + hoff) << 16);
        }
    }
}

// finish: 16 lanes per row (16 rows/block, grid 4096 -> TLP-saturated).
// Lane j resolves ONE code per candidate section: k = base + 16*(j>>2)+(j&3)
// — identical per-code arithmetic to the 1-thread version. Index-only output.
__global__ void vq_finish(const float* __restrict__ z, const float* __restrict__ emb,
                          const float* __restrict__ ee,
                          const float* __restrict__ tU1, const int* __restrict__ tK1,
                          const float* __restrict__ tU2, const int* __restrict__ tK23,
                          const float* __restrict__ tU3, const float* __restrict__ tU4,
                          float* __restrict__ out,
                          int* __restrict__ listB, int* __restrict__ cntB) {
    const int tid = threadIdx.x;
    const int grp = tid >> 4;       // row group within block
    const int j = tid & 15;         // lane role within row
    const int row = blockIdx.x * 16 + grp;

    // merge half tuples (redundant per lane; loads broadcast within group)
    float u1 = tU1[row]; int g1 = tK1[row];
    float u2 = tU2[row];
    float u3 = tU3[row]; float u4 = tU4[row];
    int k23 = tK23[row];
    int g2 = k23 & 0xFFFF, g3 = ((unsigned)k23) >> 16;
    {
        float b1 = tU1[NROWS + row]; int h1 = tK1[NROWS + row];
        float b2 = tU2[NROWS + row];
        float b3 = tU3[NROWS + row]; float b4 = tU4[NROWS + row];
        int hk = tK23[NROWS + row];
        int h2 = hk & 0xFFFF, h3 = ((unsigned)hk) >> 16;
#define INSU(bv, bi)                                           \
        { bool q1 = (bv) < u1, q2 = (bv) < u2, q3 = (bv) < u3; \
          u4 = q3 ? u3 : fminf((bv), u4);                      \
          u3 = q2 ? u2 : (q3 ? (bv) : u3);                     \
          g3 = q2 ? g2 : (q3 ? (bi) : g3);                     \
          u2 = q1 ? u1 : (q2 ? (bv) : u2);                     \
          g2 = q1 ? g1 : (q2 ? (bi) : g2);                     \
          u1 = q1 ? (bv) : u1;                                 \
          g1 = q1 ? (bi) : g1; }
        INSU(b1, h1);
        INSU(b2, h2);
        INSU(b3, h3);
        u4 = fminf(u4, b4);
#undef INSU
    }

    // load z row (explicit register array, float4 loads)
    float zr[DIM];
    {
        const float4* zp = reinterpret_cast<const float4*>(z + (size_t)row * DIM);
#pragma unroll
        for (int i = 0; i < 16; ++i) {
            float4 a = zp[i];
            zr[4 * i + 0] = a.x; zr[4 * i + 1] = a.y; zr[4 * i + 2] = a.z; zr[4 * i + 3] = a.w;
        }
    }
    float zzs = 0.f;
#pragma unroll
    for (int i = 0; i < DIM; ++i) zzs = fmaf(zr[i], zr[i], zzs);

    // threshold: ref f32 rounding (~2.2 ulp zz) + f16-screen error + ee drop
    float delta = ((zzs > 120.f) ? 3.4e-5f : 1.7e-5f) + 2.5e-5f;

    // 4th section within delta -> exact full scan resolves (and overwrites) later
    if (j == 0 && u4 - u1 < delta) {
        int p = atomicAdd(cntB, 1);
        listB[p] = row;
    }

    // exact resolve: lane j takes code base + 16*(j>>2) + (j&3) of each section
    const float zz = pairwise_sumsq64(zr);
    const int joff = ((j >> 2) << 4) + (j & 3);
    unsigned long long bestkey = ~0ull;
    int secs[3]; int nsec = 1; secs[0] = g1;
    if (u2 - u1 < delta) {
        secs[1] = g2; nsec = 2;
        if (u3 - u1 < delta) { secs[2] = g3; nsec = 3; }
    }
    for (int si = 0; si < nsec; ++si) {
        int k = secs[si] + joff;
        float d2 = exact_d2(emb, k, zr, zz, ee[k]);
        unsigned long long key =
            (((unsigned long long)__float_as_uint(d2)) << 32) | (unsigned)k;
        bestkey = key < bestkey ? key : bestkey;
    }
    {   // min over the 16 lanes of this row
#pragma unroll
        for (int d = 1; d < 16; d <<= 1) {
            unsigned long long o = __shfl_xor(bestkey, d);
            bestkey = o < bestkey ? o : bestkey;
        }
    }
    if (j == 0) out[OUT_IDX_OFF + row] = (float)(int)(bestkey & 0xFFFFFFFFu);
}

// emit: epilogue, fully coalesced. Per block: 64 rows. Stage z + chosen emb
// rows in LDS (stride-65 pad), write NCHW d-major (256B segments),
// rowloss + block loss partial.
__launch_bounds__(256, 4)
__global__ void vq_emit(const float* __restrict__ z, const float* __restrict__ emb,
                        float* __restrict__ out, float* __restrict__ rowloss,
                        double* __restrict__ part) {
    __shared__ float zs[64 * 65];
    __shared__ float qs[64 * 65];
    __shared__ float ls[64 * 5];
    const int tid = threadIdx.x;
    const int rl = tid >> 2;        // row within block
    const int j = tid & 3;          // quarter-row role
    const int row = blockIdx.x * 64 + rl;

    // stage z: thread tid loads its 64B chunk (fully coalesced), scalar LDS writes
    {
        const float4* zp = reinterpret_cast<const float4*>(
            z + (size_t)blockIdx.x * 4096 + (size_t)tid * 16);
        float4 a = zp[0], b = zp[1], c = zp[2], d = zp[3];
        float v[16] = {a.x, a.y, a.z, a.w, b.x, b.y, b.z, b.w,
                       c.x, c.y, c.z, c.w, d.x, d.y, d.z, d.w};
        float* dst = &zs[rl * 65 + j * 16];
#pragma unroll
        for (int i = 0; i < 16; ++i) dst[i] = v[i];
    }
    // stage chosen emb row (4-lane cooperative, 64B per lane)
    {
        const int kb = (int)out[OUT_IDX_OFF + row];
        const float4* qp = reinterpret_cast<const float4*>(
            emb + (size_t)kb * DIM + j * 16);
        float4 a = qp[0], b = qp[1], c = qp[2], d = qp[3];
        float v[16] = {a.x, a.y, a.z, a.w, b.x, b.y, b.z, b.w,
                       c.x, c.y, c.z, c.w, d.x, d.y, d.z, d.w};
        float* dst = &qs[rl * 65 + j * 16];
#pragma unroll
        for (int i = 0; i < 16; ++i) dst[i] = v[i];
    }
    __syncthreads();

    // write phase: wave w covers d in [16w, 16w+16); lanes = 64 consecutive hw
    const int hw_l = tid & 63;
    const int w = tid >> 6;
    const int bimg = row >> 12;
    const int hwb = (blockIdx.x * 64) & 4095;
    float* ob = out + (size_t)bimg * 262144 + hwb + hw_l;
    float lp = 0.f;
#pragma unroll
    for (int k = 0; k < 16; ++k) {
        const int d = w * 16 + k;
        float qv = qs[hw_l * 65 + d];
        float zv = zs[hw_l * 65 + d];
        float df = qv - zv;
        lp = fmaf(df, df, lp);
        ob[(size_t)d * 4096] = qv;
    }
    ls[hw_l * 5 + w] = lp;
    __syncthreads();

    // rowloss + block partial (wave 0)
    if (tid < 64) {
        float r01 = ls[tid * 5 + 0] + ls[tid * 5 + 1];
        float r23 = ls[tid * 5 + 2] + ls[tid * 5 + 3];
        float rsum = r01 + r23;
        rowloss[blockIdx.x * 64 + tid] = rsum;
        double s = (double)rsum;
#pragma unroll
        for (int d = 1; d < 64; d <<= 1) s += __shfl_xor(s, d);
        if (tid == 0) atomicAdd(&part[blockIdx.x >> 2], s);
    }
}

// exact full scan for rows with 4+ near-tied sections (block per row, grid-stride)
__global__ void vq_fallback(const float* __restrict__ z, const float* __restrict__ emb,
                            const float* __restrict__ ee, const int* __restrict__ listB,
                            const int* __restrict__ cntB, float* __restrict__ out,
                            const float* __restrict__ rowloss, double* __restrict__ part) {
    __shared__ float sZ[DIM];
    __shared__ unsigned long long sK[4];
    __shared__ int sKb;
    const int n = *cntB;
    const int tid = threadIdx.x;
    const int lane = tid & 63;
    const int w = tid >> 6;

    for (int i = blockIdx.x; i < n; i += 1024) {
        const int row = listB[i];
        __syncthreads();
        if (tid < DIM) sZ[tid] = z[(size_t)row * DIM + tid];
        __syncthreads();
        float zr[DIM];
#pragma unroll
        for (int q = 0; q < DIM; ++q) zr[q] = sZ[q];
        const float zz = pairwise_sumsq64(zr);

        unsigned long long best = ~0ull;
#pragma unroll 1
        for (int j = 0; j < 16; ++j) {
            int c = tid + j * 256;
            float d2 = exact_d2(emb, c, zr, zz, ee[c]);
            unsigned long long key =
                (((unsigned long long)__float_as_uint(d2)) << 32) | (unsigned)c;
            best = key < best ? key : best;
        }
#pragma unroll
        for (int d = 1; d < 64; d <<= 1) {
            unsigned long long o2 = __shfl_xor(best, d);
            best = o2 < best ? o2 : best;
        }
        if (lane == 0) sK[w] = best;
        __syncthreads();
        if (tid == 0) {
            unsigned long long b = sK[0];
            b = sK[1] < b ? sK[1] : b;
            b = sK[2] < b ? sK[2] : b;
            b = sK[3] < b ? sK[3] : b;
            sKb = (int)(b & 0xFFFFFFFFu);
        }
        __syncthreads();
        const int kb = sKb;
        if (tid < DIM) {
            const float qv = emb[(size_t)kb * DIM + tid];
            const float zv = sZ[tid];
            int bimg = row >> 12, hw = row & 4095;
            out[(size_t)bimg * 262144 + (size_t)tid * 4096 + hw] = qv;
            float lp = (qv - zv) * (qv - zv);
#pragma unroll
            for (int d = 1; d < 64; d <<= 1) lp += __shfl_xor(lp, d);
            if (tid == 0) {
                // adjust fused loss partials by the correction delta
                double dl = (double)lp - (double)rowloss[row];
                atomicAdd(&part[row >> 8], dl);
                out[OUT_IDX_OFF + row] = (float)kb;
            }
        }
    }
}

__global__ void vq_red2(const double* __restrict__ part, float* __restrict__ out_loss) {
    __shared__ double sd[256];
    sd[threadIdx.x] = part[threadIdx.x];
    __syncthreads();
    for (int st = 128; st > 0; st >>= 1) {
        if (threadIdx.x < st) sd[threadIdx.x] += sd[threadIdx.x + st];
        __syncthreads();
    }
    if (threadIdx.x == 0) out_loss[0] = (float)(0.25 * sd[0]);
}

extern "C" void kernel_launch(void* const* d_in, const int* in_sizes, int n_in,
                              void* d_out, int out_size, void* d_ws, size_t ws_size,
                              hipStream_t stream) {
    const float* z = (const float*)d_in[0];
    const float* emb = (const float*)d_in[1];
    float* out = (float*)d_out;
    char* ws = (char*)d_ws;

    _Float16* ehi = (_Float16*)(ws + WS_EHI);
    float* ee = (float*)(ws + WS_EE);
    float* rowloss = (float*)(ws + WS_RLOSS);
    float* tU1 = (float*)(ws + WS_TU1);
    int*   tK1 = (int*)(ws + WS_TK1);
    float* tU2 = (float*)(ws + WS_TU2);
    int*   tK23 = (int*)(ws + WS_TK23);
    float* tU3 = (float*)(ws + WS_TU3);
    float* tU4 = (float*)(ws + WS_TU4);
    int* listB = (int*)(ws + WS_LISTB);
    int* cntB  = (int*)(ws + WS_CNTB);
    double* part = (double*)(ws + WS_PART);

    vq_prep<<<NCODES / 256, 256, 0, stream>>>(emb, ehi, ee, cntB, part);
    vq_scan<<<dim3(NROWS / 128, 2), 256, 0, stream>>>(z, ehi, tU1, tK1, tU2, tK23, tU3, tU4);
    vq_finish<<<NROWS / 16, 256, 0, stream>>>(z, emb, ee, tU1, tK1, tU2, tK23, tU3, tU4,
                                              out, listB, cntB);
    vq_emit<<<NROWS / 64, 256, 0, stream>>>(z, emb, out, rowloss, part);
    vq_fallback<<<1024, 256, 0, stream>>>(z, emb, ee, listB, cntB, out, rowloss, part);
    vq_red2<<<1, 256, 0, stream>>>(part, out + OUT_LOSS_OFF);
}